// Round 1
// baseline (102.900 us; speedup 1.0000x reference)
//
#include <hip/hip_runtime.h>
#include <hip/hip_bf16.h>
#include <math.h>

#define NA 4096
#define NM 64
#define NQ 64
#define NH 64

// One block (64 threads = 1 wave) per atom n.
// LDS: W0[z] staged with pad-65 rows so both h-major (forward) and q-major
// (backward) reads are bank-conflict-free.
__global__ __launch_bounds__(64) void tnep_main(
    const float* __restrict__ desc,
    const float* __restrict__ grad,
    const int*   __restrict__ gidx,
    const float* __restrict__ pos,
    const int*   __restrict__ Zp,
    const float* __restrict__ box,
    const float* __restrict__ amaskp,
    const float* __restrict__ nmaskp,
    const float* __restrict__ W0,
    const float* __restrict__ b0,
    const float* __restrict__ W1,
    const float* __restrict__ W0p,
    const float* __restrict__ b0p,
    const float* __restrict__ W1p,
    const float* __restrict__ b1p,
    float* __restrict__ ws,
    float* __restrict__ out,
    int mode)
{
    const int n    = blockIdx.x;
    const int lane = threadIdx.x;
    const int z    = Zp[n];
    const float amask = amaskp[n];

    __shared__ float sdesc[NQ];
    __shared__ float sW0[NQ * 65];
    __shared__ float sde_da[NH];
    __shared__ float sde_dq[NQ];
    __shared__ float sdr[NM * 4];

    sdesc[lane] = desc[n * NQ + lane];

    // Stage W0[z] (16 KB) into LDS, padded stride 65.
    const float4* W0v = reinterpret_cast<const float4*>(W0 + (size_t)z * NQ * NH);
#pragma unroll
    for (int i = 0; i < 16; ++i) {
        float4 v = W0v[i * 64 + lane];
        int q  = 4 * i + (lane >> 4);
        int h0 = 4 * (lane & 15);
        float* p = &sW0[q * 65 + h0];
        p[0] = v.x; p[1] = v.y; p[2] = v.z; p[3] = v.w;
    }

    // Phase 1.5: per-pair minimal-image displacement scalars (lane = m).
    // Fold in -1 and neighbor_mask^2 (mask hits forces AND pol_outer in ref).
    {
        int g = gidx[n * NM + lane];
        float Lx = box[0], Ly = box[4], Lz = box[8];
        float dx = pos[g * 3 + 0] - pos[n * 3 + 0];
        float dy = pos[g * 3 + 1] - pos[n * 3 + 1];
        float dz = pos[g * 3 + 2] - pos[n * 3 + 2];
        dx -= Lx * rintf(dx * (1.0f / Lx));   // rintf = round-half-even = jnp.round
        dy -= Ly * rintf(dy * (1.0f / Ly));
        dz -= Lz * rintf(dz * (1.0f / Lz));
        float nm = nmaskp[n * NM + lane];
        float w  = -nm * nm;
        sdr[lane * 4 + 0] = w * dx;
        sdr[lane * 4 + 1] = w * dy;
        sdr[lane * 4 + 2] = w * dz;
        sdr[lane * 4 + 3] = 0.0f;
    }
    __syncthreads();

    // Forward pass, tensor + pol ANN fused (lane = h).
    float a_t = b0 [z * NH + lane];
    float a_p = b0p[z * NH + lane];
    const float* W0prow = W0p + (size_t)z * NQ * NH;
#pragma unroll 8
    for (int q = 0; q < NQ; ++q) {
        float d = sdesc[q];
        a_t = fmaf(d, sW0[q * 65 + lane], a_t);
        a_p = fmaf(d, W0prow[q * NH + lane], a_p);   // small, L1/L2-cached
    }
    float hT = tanhf(a_t) * amask;
    float hP = tanhf(a_p) * amask;
    sde_da[lane] = (1.0f - hT * hT) * W1[z * NH + lane];
    float fp = hP * W1p[z * NH + lane];
#pragma unroll
    for (int s = 1; s < 64; s <<= 1) fp += __shfl_xor(fp, s, 64);
    __syncthreads();

    // Backward: de_dq[q] = sum_h de_da[h] * W0[z][q][h]   (lane = q).
    float dq = 0.0f;
#pragma unroll 8
    for (int h = 0; h < NH; ++h)
        dq = fmaf(sde_da[h], sW0[lane * 65 + h], dq);
    sde_dq[lane] = dq;
    __syncthreads();

    // Phase 2: stream gradients[n] (48 KB). lanes: c = lane>>4 (c==3 idle),
    // qg = lane&15 -> one dwordx4 wave-load covers a full (m, c=0..2) 768B row set.
    const int c  = lane >> 4;
    const int qg = lane & 15;
    float4 dq4 = *reinterpret_cast<const float4*>(&sde_dq[4 * qg]);
    float acc0 = 0.f, acc1 = 0.f, acc2 = 0.f;
    if (c < 3) {
        const float4* gp = reinterpret_cast<const float4*>(grad + (size_t)n * NM * 3 * NQ)
                           + c * 16 + qg;
#pragma unroll 4
        for (int m = 0; m < NM; ++m) {
            float4 g4 = gp[m * 48];
            float s = fmaf(dq4.x, g4.x, fmaf(dq4.y, g4.y, fmaf(dq4.z, g4.z, dq4.w * g4.w)));
            float4 d4 = *reinterpret_cast<const float4*>(&sdr[m * 4]);  // broadcast
            acc0 = fmaf(d4.x, s, acc0);
            acc1 = fmaf(d4.y, s, acc1);
            acc2 = fmaf(d4.z, s, acc2);
        }
    }
    // Reduce within each 16-lane (same c) group.
#pragma unroll
    for (int s = 1; s < 16; s <<= 1) {
        acc0 += __shfl_xor(acc0, s, 64);
        acc1 += __shfl_xor(acc1, s, 64);
        acc2 += __shfl_xor(acc2, s, 64);
    }

    float fpv = (fp + b1p[0]) * amask;

    if (mode == 0) {
        // Deterministic path: per-block partials to ws, no atomics.
        float* wsb = ws + n * 16;
        if (qg == 0 && c < 3) {
            wsb[c * 3 + 0] = acc0;   // slot c*3+a stores pm[a][b=c]
            wsb[c * 3 + 1] = acc1;
            wsb[c * 3 + 2] = acc2;
        }
        if (lane == 0) wsb[9] = fpv;
    } else {
        // Fallback (tiny ws): atomic accumulation directly into out[6].
        if (qg == 0 && c < 3) {
            const int map[9] = {0, -1, 5, 3, 1, -1, -1, 4, 2};
            float av0 = acc0, av1 = acc1, av2 = acc2;
            int m0 = map[c * 3 + 0], m1 = map[c * 3 + 1], m2 = map[c * 3 + 2];
            if (m0 >= 0) atomicAdd(out + m0, av0);
            if (m1 >= 0) atomicAdd(out + m1, av1);
            if (m2 >= 0) atomicAdd(out + m2, av2);
        }
        if (lane == 0) {
            atomicAdd(out + 0, fpv);
            atomicAdd(out + 1, fpv);
            atomicAdd(out + 2, fpv);
        }
    }
}

__global__ __launch_bounds__(256) void tnep_reduce(const float* __restrict__ ws,
                                                   float* __restrict__ out)
{
    __shared__ float s[256];
    int t = threadIdx.x;
    int k = t & 15;
    int r = t >> 4;
    float v = 0.f;
    if (k < 10) {
        for (int b = r; b < NA; b += 16) v += ws[b * 16 + k];  // coalesced: t+256*i
    }
    s[t] = v;
    __syncthreads();
    if (t < 16) {
        float tot = 0.f;
#pragma unroll
        for (int j = 0; j < 16; ++j) tot += s[j * 16 + t];
        s[t] = tot;   // each thread only re-reads its own s[t] among [0,16)
    }
    __syncthreads();
    if (t == 0) {
        float S = s[9];                 // scalar (pol) sum
        out[0] = s[0] + S;              // pm00
        out[1] = s[4] + S;              // pm11
        out[2] = s[8] + S;              // pm22
        out[3] = s[3];                  // pm01
        out[4] = s[7];                  // pm12
        out[5] = s[2];                  // pm20
    }
}

__global__ void tnep_zero(float* out)
{
    if (threadIdx.x < 6) out[threadIdx.x] = 0.f;
}

extern "C" void kernel_launch(void* const* d_in, const int* in_sizes, int n_in,
                              void* d_out, int out_size, void* d_ws, size_t ws_size,
                              hipStream_t stream)
{
    const float* desc  = (const float*)d_in[0];
    const float* grad  = (const float*)d_in[1];
    const int*   gidx  = (const int*)  d_in[2];
    const float* pos   = (const float*)d_in[3];
    const int*   Zp    = (const int*)  d_in[4];
    const float* box   = (const float*)d_in[5];
    const float* amask = (const float*)d_in[6];
    const float* nmask = (const float*)d_in[7];
    const float* W0    = (const float*)d_in[8];
    const float* b0    = (const float*)d_in[9];
    const float* W1    = (const float*)d_in[10];
    // d_in[11] = b1 (unused by reference)
    const float* W0p   = (const float*)d_in[12];
    const float* b0p   = (const float*)d_in[13];
    const float* W1p   = (const float*)d_in[14];
    const float* b1p   = (const float*)d_in[15];
    float* out = (float*)d_out;
    float* ws  = (float*)d_ws;

    int mode = (ws_size >= (size_t)NA * 16 * sizeof(float)) ? 0 : 1;
    if (mode == 1) tnep_zero<<<1, 64, 0, stream>>>(out);
    tnep_main<<<NA, 64, 0, stream>>>(desc, grad, gidx, pos, Zp, box, amask, nmask,
                                     W0, b0, W1, W0p, b0p, W1p, b1p, ws, out, mode);
    if (mode == 0) tnep_reduce<<<1, 256, 0, stream>>>(ws, out);
}